// Round 6
// baseline (707.996 us; speedup 1.0000x reference)
//
#include <hip/hip_runtime.h>

// VQ-VAE quantizer: z [16,4096,64] f32, embedding [1024,64] f32.
// Outputs concatenated in d_out (float32): [0]=loss, [1..4194304]=z_q,
// [4194305..]=argmin indices (as float).
//
// Correctness-critical (verified absmax 0.0 in R0/R1/R2/R4/R5): per-(row,code)
// d = fmaf(-2,dot,(zz+ee)) with dot accumulated as p0..p3 over 16 float4
// chunks combined (p0+p1)+(p2+p3); zz/ee use numpy's pairwise 8-accumulator
// tree with fp-contract OFF; first-index argmin via strict < on ascending
// scans + explicit (val==, idx<) tie-break on all tree merges. Loss: per-row
// sequential col sum + shfl tree + one atomic/block (verified structure).
//
// R7 change: REGISTER-TILED GEMM through LDS. Evidence: R1/R5 both move
// 256MB through the scalar K$ path in ~205us at 36-38% VALUBusy regardless
// of reuse pattern -> scalar delivery is a hard ~2.2 B/cyc/CU throughput
// wall (7x too slow for the VALU). R2 proved uniform VMEM broadcast worse;
// R4 proved codes-in-VGPR spills. Fix: both operands served from LDS with
// per-lane-DISTINCT addresses (full LDS bandwidth, zero scalar traffic in
// the hot loop): lane tile 4 rows x 2 codes = 32 fmaf per 6 ds_read_b128;
// stride-68 padding + strided row map (i + 8rr) -> conflict-free reads.
// e staged in 16x 64-code tiles with register prefetch (loads for tile t+1
// issued during compute of tile t). Epilogue folded in (removes the ~80us
// vq_finish kernel); z_q/loss read z bits from the staged LDS tile.

#define D 64
#define NE 1024
#define ROWS 32              // rows per block
#define TCODES 64            // codes per LDS tile
#define NTILES (NE / TCODES) // 16
#define TPB 256              // 4 waves
#define WAVES 4
#define ZSTR 68              // padded LDS row stride (floats): 4*68=272B, 16B-aligned,
                             // 68%32=4 banks -> 8 row-groups hit 8 distinct bank-quads

__global__ __launch_bounds__(TPB, 3) void vq_kernel(const float* __restrict__ z,
                                                    const float* __restrict__ emb,
                                                    float* __restrict__ out_loss,
                                                    float* __restrict__ out_zq,
                                                    float* __restrict__ out_idx,
                                                    float loss_scale) {
    __shared__ __align__(16) float z_lds[ROWS * ZSTR];    // 8.5 KB
    __shared__ __align__(16) float e_lds[TCODES * ZSTR];  // 17 KB
    __shared__ float ee_lds[NE];                          // 4 KB
    __shared__ float zz_lds[ROWS];
    __shared__ float smv[WAVES * ROWS];
    __shared__ int   smi[WAVES * ROWS];

    const int tid  = threadIdx.x;
    const int lane = tid & 63;
    const int w    = tid >> 6;          // wave id: codes [16w, 16w+16) of each tile
    const int i8   = lane & 7;          // row-group: rows {i8 + 8rr}
    const int jg   = lane >> 3;         // code-group: codes {16w + jg + 8cc}
    const size_t blockRow = (size_t)blockIdx.x * ROWS;

    // --- Stage z tile (32x64) coalesced into padded LDS (512 f4, 2/thread). ---
    {
        const float4* zg4 = (const float4*)(z + blockRow * D);
#pragma unroll
        for (int it = 0; it < 2; ++it) {
            int idx = tid + it * TPB;
            float4 v = zg4[idx];
            *(float4*)&z_lds[(idx >> 4) * ZSTR + (idx & 15) * 4] = v;
        }
    }

    // --- Prefetch e-tile 0 into registers (1024 f4, 4/thread). ---
    float4 eR0, eR1, eR2, eR3;
    {
        const float4* eg4 = (const float4*)emb;
        eR0 = eg4[tid];       eR1 = eg4[tid + 256];
        eR2 = eg4[tid + 512]; eR3 = eg4[tid + 768];
    }

    // --- ee for all 1024 codes, 4/thread (verified numpy-pairwise tree). ---
    {
#pragma clang fp contract(off)
#pragma unroll
        for (int cc = 0; cc < 4; ++cc) {
            const int j = tid + cc * TPB;
            const float4* e4 = (const float4*)(emb + ((size_t)j << 6));
            float4 a = e4[0], b = e4[1];
            float r[8];
            r[0]=a.x*a.x; r[1]=a.y*a.y; r[2]=a.z*a.z; r[3]=a.w*a.w;
            r[4]=b.x*b.x; r[5]=b.y*b.y; r[6]=b.z*b.z; r[7]=b.w*b.w;
#pragma unroll
            for (int g = 1; g < 8; ++g) {
                float4 c = e4[2*g], e = e4[2*g + 1];
                r[0]=r[0]+c.x*c.x; r[1]=r[1]+c.y*c.y;
                r[2]=r[2]+c.z*c.z; r[3]=r[3]+c.w*c.w;
                r[4]=r[4]+e.x*e.x; r[5]=r[5]+e.y*e.y;
                r[6]=r[6]+e.z*e.z; r[7]=r[7]+e.w*e.w;
            }
            ee_lds[j] = ((r[0]+r[1])+(r[2]+r[3])) + ((r[4]+r[5])+(r[6]+r[7]));
        }
    }
    __syncthreads();   // z_lds, ee_lds ready

    // --- zz per row (verified tree) from the staged z bits. ---
    if (tid < ROWS) {
        float zr[D];
#pragma unroll
        for (int c = 0; c < 16; ++c) {
            float4 v = *(const float4*)&z_lds[tid * ZSTR + c * 4];
            zr[4*c+0]=v.x; zr[4*c+1]=v.y; zr[4*c+2]=v.z; zr[4*c+3]=v.w;
        }
        {
#pragma clang fp contract(off)
            float r[8];
#pragma unroll
            for (int jj = 0; jj < 8; ++jj) { float t = zr[jj]*zr[jj]; r[jj] = t; }
#pragma unroll
            for (int i = 8; i < 64; i += 8) {
#pragma unroll
                for (int jj = 0; jj < 8; ++jj) { float t = zr[i+jj]*zr[i+jj]; r[jj] = r[jj] + t; }
            }
            zz_lds[tid] = ((r[0]+r[1])+(r[2]+r[3])) + ((r[4]+r[5])+(r[6]+r[7]));
        }
    }
    __syncthreads();   // zz ready; e_lds free to write

    float zzr[4];
#pragma unroll
    for (int rr = 0; rr < 4; ++rr) zzr[rr] = zz_lds[i8 + 8 * rr];

    float rb[4];  int rbj[4];
#pragma unroll
    for (int rr = 0; rr < 4; ++rr) { rb[rr] = __builtin_inff(); rbj[rr] = 0; }

    // --- Main loop: 16 tiles of 64 codes. ---
    for (int t = 0; t < NTILES; ++t) {
        // Write the prefetched tile t into LDS.
        {
            int idx0 = tid;
            *(float4*)&e_lds[(idx0 >> 4) * ZSTR + (idx0 & 15) * 4] = eR0;
            int idx1 = tid + 256;
            *(float4*)&e_lds[(idx1 >> 4) * ZSTR + (idx1 & 15) * 4] = eR1;
            int idx2 = tid + 512;
            *(float4*)&e_lds[(idx2 >> 4) * ZSTR + (idx2 & 15) * 4] = eR2;
            int idx3 = tid + 768;
            *(float4*)&e_lds[(idx3 >> 4) * ZSTR + (idx3 & 15) * 4] = eR3;
        }
        // Issue prefetch of tile t+1 (latency hides under compute of tile t).
        if (t < NTILES - 1) {
            const float4* eg4 = (const float4*)(emb + (size_t)(t + 1) * TCODES * D);
            eR0 = eg4[tid];       eR1 = eg4[tid + 256];
            eR2 = eg4[tid + 512]; eR3 = eg4[tid + 768];
        }
        __syncthreads();   // e_lds tile t ready

        // 4 rows x 2 codes per lane; p0..p3 live in acc.{x,y,z,w} (verified order).
        float4 acc[4][2];
#pragma unroll
        for (int rr = 0; rr < 4; ++rr)
#pragma unroll
            for (int cc = 0; cc < 2; ++cc)
                acc[rr][cc] = make_float4(0.f, 0.f, 0.f, 0.f);

#pragma unroll
        for (int c = 0; c < 16; ++c) {
            float4 zf[4], ef[2];
#pragma unroll
            for (int rr = 0; rr < 4; ++rr)
                zf[rr] = *(const float4*)&z_lds[(i8 + 8*rr) * ZSTR + c * 4];
#pragma unroll
            for (int cc = 0; cc < 2; ++cc)
                ef[cc] = *(const float4*)&e_lds[((w << 4) + jg + (cc << 3)) * ZSTR + c * 4];
#pragma unroll
            for (int rr = 0; rr < 4; ++rr)
#pragma unroll
                for (int cc = 0; cc < 2; ++cc) {
                    acc[rr][cc].x = fmaf(zf[rr].x, ef[cc].x, acc[rr][cc].x);
                    acc[rr][cc].y = fmaf(zf[rr].y, ef[cc].y, acc[rr][cc].y);
                    acc[rr][cc].z = fmaf(zf[rr].z, ef[cc].z, acc[rr][cc].z);
                    acc[rr][cc].w = fmaf(zf[rr].w, ef[cc].w, acc[rr][cc].w);
                }
        }

        const int cbase = t * TCODES + (w << 4) + jg;   // code of cc=0
        const float ee0 = ee_lds[cbase];
        const float ee1 = ee_lds[cbase + 8];
#pragma unroll
        for (int rr = 0; rr < 4; ++rr) {
            float dot0 = (acc[rr][0].x + acc[rr][0].y) + (acc[rr][0].z + acc[rr][0].w);
            float dot1 = (acc[rr][1].x + acc[rr][1].y) + (acc[rr][1].z + acc[rr][1].w);
            float t10 = zzr[rr] + ee0;            // mirrors np (zz + ee) rounding
            float t11 = zzr[rr] + ee1;
            float d0 = fmaf(-2.0f, dot0, t10);
            float d1 = fmaf(-2.0f, dot1, t11);
            float cv = d0; int cj = cbase;        // cbase < cbase+8: ascending
            if (d1 < cv) { cv = d1; cj = cbase + 8; }
            // Cross-tile: for fixed lane, indices ascend with t -> strict <.
            if (cv < rb[rr]) { rb[rr] = cv; rbj[rr] = cj; }
        }
        __syncthreads();   // all reads of e_lds done before next overwrite
    }

    // --- Cross-lane (jg) butterfly per row: tie -> smaller index. ---
#pragma unroll
    for (int rr = 0; rr < 4; ++rr) {
        float bv = rb[rr]; int bj = rbj[rr];
#pragma unroll
        for (int off = 8; off <= 32; off <<= 1) {
            float ov = __shfl_xor(bv, off);
            int   oi = __shfl_xor(bj, off);
            if (ov < bv || (ov == bv && oi < bj)) { bv = ov; bj = oi; }
        }
        if (jg == 0) {
            smv[w * ROWS + i8 + 8*rr] = bv;
            smi[w * ROWS + i8 + 8*rr] = bj;
        }
    }
    __syncthreads();

    // --- Epilogue: merge 4 waves (interleaved codes -> idx-aware tie),
    //     then verified gather/store/loss structure. ---
    const int erow = tid & 31;          // row handled by this thread
    const int eg   = tid >> 5;          // col-group: stores cols [8eg, 8eg+8)

    float best = smv[erow]; int bi = smi[erow];
#pragma unroll
    for (int s2 = 1; s2 < WAVES; ++s2) {
        float v  = smv[s2 * ROWS + erow];
        int   ii = smi[s2 * ROWS + erow];
        if (v < best || (v == best && ii < bi)) { best = v; bi = ii; }
    }

    const float4* qe4 = (const float4*)(emb + ((size_t)bi << 6));
    float s = 0.f;
    float* orow = out_zq + (blockRow + erow) * D;
#pragma unroll
    for (int c = 0; c < 16; ++c) {
        float4 q  = qe4[c];
        float4 zv = *(const float4*)&z_lds[erow * ZSTR + c * 4];
        float d0 = q.x - zv.x, d1 = q.y - zv.y, d2 = q.z - zv.z, d3 = q.w - zv.w;
        s += d0*d0; s += d1*d1; s += d2*d2; s += d3*d3;
        if ((c >> 1) == eg) {                  // each (row,col) stored exactly once
            // out_zq is d_out+1 (4B-aligned) -> dword stores.
            orow[4*c+0] = zv.x + d0; orow[4*c+1] = zv.y + d1;
            orow[4*c+2] = zv.z + d2; orow[4*c+3] = zv.w + d3;
        }
    }

    if (eg == 0) {                             // threads 0..31 (wave 0)
        out_idx[blockRow + erow] = (float)bi;
#pragma unroll
        for (int off = 16; off; off >>= 1) s += __shfl_down(s, off);
        if (tid == 0) atomicAdd(out_loss, s * loss_scale);
    }
}

extern "C" void kernel_launch(void* const* d_in, const int* in_sizes, int n_in,
                              void* d_out, int out_size, void* d_ws, size_t ws_size,
                              hipStream_t stream) {
    const float* z   = (const float*)d_in[0];
    const float* emb = (const float*)d_in[1];
    const int nz = in_sizes[0];          // 4194304
    const int N  = nz / D;               // 65536 rows

    float* out      = (float*)d_out;
    float* out_zq   = out + 1;
    float* out_idx  = out + 1 + (size_t)nz;

    const float loss_scale = 1.25f / (float)nz;

    hipMemsetAsync(out, 0, sizeof(float), stream);  // loss accumulator
    vq_kernel<<<N / ROWS, TPB, 0, stream>>>(z, emb, out, out_zq, out_idx, loss_scale);
}

// Round 8
// 217.555 us; speedup vs baseline: 3.2543x; 3.2543x over previous
//
#include <hip/hip_runtime.h>

// VQ-VAE quantizer: z [16,4096,64] f32, embedding [1024,64] f32.
// Outputs concatenated in d_out (float32): [0]=loss, [1..4194304]=z_q,
// [4194305..]=argmin indices (as float).
//
// Correctness-critical (verified absmax 0.0 in R0/R1/R2/R4/R5/R6): per-(row,
// code) d = fmaf(-2,dot,(zz+ee)); dot accumulated as p0..p3 over 16 float4
// chunks combined (p0+p1)+(p2+p3); zz/ee numpy-pairwise 8-accumulator tree,
// fp-contract OFF; first-index argmin via strict < on in-lane ascending scans
// + (val==, idx<) tie-break on every tree merge. Loss: per-row sequential col
// sum + 64-lane shfl tree + one atomic/block (R1's verified epilogue).
//
// R8 (resubmit with ee_kernel pragma-placement compile fix): fix R6's spill,
// keep the LDS-GEMM structure. Evidence: R6's WRITE_SIZE=1.47GB / FETCH=643MB
// = acc spilled once per tile (2.8KB/thread scratch) because the fully-
// unrolled 16-chunk c-loop hoisted 96 ds_reads; scratch thrashed L2 ->
// memory-bound. Fixes:
//  - #pragma unroll 2 on the c-loop (small scheduler window).
//  - wave split 8 row-groups x 8 code-groups (4r x 4c per lane): every LDS
//    read is 8 unique lines x 8-lane broadcast, conflict-free; LDS cost
//    ~2cyc/instr -> VALU-bound.
//  - waves = 2(row-half) x 2(code-half): merge = 3-step jg butterfly + one
//    2-way LDS merge (tie-aware, same semantics as verified R6 merge).
//  - ee precomputed once by a tiny kernel (same bitwise tree) instead of
//    redundantly per block.

#define D 64
#define NE 1024
#define ROWS 64              // rows per block
#define TCODES 64            // codes per LDS tile
#define NTILES 16
#define TPB 256              // 4 waves = 2 row-halves x 2 code-halves
#define ZSTR 68              // padded LDS row stride (floats)

__global__ __launch_bounds__(64, 4) void ee_kernel(const float* __restrict__ emb,
                                                   float* __restrict__ ee_ws) {
    const int j = blockIdx.x * 64 + threadIdx.x;   // 16 blocks x 64 = 1024 codes
    {
#pragma clang fp contract(off)
        const float4* e4 = (const float4*)(emb + ((size_t)j << 6));
        float4 a = e4[0], b = e4[1];
        float r[8];
        r[0]=a.x*a.x; r[1]=a.y*a.y; r[2]=a.z*a.z; r[3]=a.w*a.w;
        r[4]=b.x*b.x; r[5]=b.y*b.y; r[6]=b.z*b.z; r[7]=b.w*b.w;
#pragma unroll
        for (int g = 1; g < 8; ++g) {
            float4 c = e4[2*g], e = e4[2*g + 1];
            r[0]=r[0]+c.x*c.x; r[1]=r[1]+c.y*c.y;
            r[2]=r[2]+c.z*c.z; r[3]=r[3]+c.w*c.w;
            r[4]=r[4]+e.x*e.x; r[5]=r[5]+e.y*e.y;
            r[6]=r[6]+e.z*e.z; r[7]=r[7]+e.w*e.w;
        }
        ee_ws[j] = ((r[0]+r[1])+(r[2]+r[3])) + ((r[4]+r[5])+(r[6]+r[7]));
    }
}

__global__ __launch_bounds__(TPB, 3) void vq_kernel(const float* __restrict__ z,
                                                    const float* __restrict__ emb,
                                                    const float* __restrict__ ee_ws,
                                                    float* __restrict__ out_loss,
                                                    float* __restrict__ out_zq,
                                                    float* __restrict__ out_idx,
                                                    float loss_scale) {
    __shared__ __align__(16) float z_lds[ROWS * ZSTR];    // 17.4 KB
    __shared__ __align__(16) float e_lds[TCODES * ZSTR];  // 17.4 KB
    __shared__ float ee_lds[NE];                          // 4 KB
    __shared__ float zz_lds[ROWS];
    __shared__ float smv[2 * ROWS];
    __shared__ int   smi[2 * ROWS];

    const int tid  = threadIdx.x;
    const int lane = tid & 63;
    const int w    = tid >> 6;
    const int rh   = w & 1;             // row half: rows [32rh, 32rh+32)
    const int ch   = w >> 1;            // code half of each tile
    const int i8   = lane & 7;          // row group: rows 32rh + i8 + 8rr
    const int jg   = lane >> 3;         // code group: codes 32ch + jg + 8cc
    const size_t blockRow = (size_t)blockIdx.x * ROWS;
    const int zrow0 = (rh << 5) + i8;

    // --- Stage z tile (64x64) into padded LDS (1024 f4, 4/thread, coalesced). ---
    {
        const float4* zg4 = (const float4*)(z + blockRow * D);
#pragma unroll
        for (int it = 0; it < 4; ++it) {
            int idx = tid + it * TPB;
            float4 v = zg4[idx];
            *(float4*)&z_lds[(idx >> 4) * ZSTR + (idx & 15) * 4] = v;
        }
    }
    // --- ee table from workspace (bit-identical, precomputed once). ---
    {
        float4 v = ((const float4*)ee_ws)[tid];
        *(float4*)&ee_lds[tid * 4] = v;
    }
    // --- Prefetch e-tile 0 into registers (16 KB, 4 f4/thread). ---
    float4 pe0, pe1, pe2, pe3;
    {
        const float4* eg4 = (const float4*)emb;
        pe0 = eg4[tid];       pe1 = eg4[tid + 256];
        pe2 = eg4[tid + 512]; pe3 = eg4[tid + 768];
    }
    __syncthreads();   // z_lds, ee_lds ready

    // --- zz per row (verified numpy tree) from the staged z bits. ---
    if (tid < ROWS) {
        float zr[D];
#pragma unroll
        for (int c = 0; c < 16; ++c) {
            float4 v = *(const float4*)&z_lds[tid * ZSTR + c * 4];
            zr[4*c+0]=v.x; zr[4*c+1]=v.y; zr[4*c+2]=v.z; zr[4*c+3]=v.w;
        }
        {
#pragma clang fp contract(off)
            float r[8];
#pragma unroll
            for (int jj = 0; jj < 8; ++jj) { float t = zr[jj]*zr[jj]; r[jj] = t; }
#pragma unroll
            for (int i = 8; i < 64; i += 8) {
#pragma unroll
                for (int jj = 0; jj < 8; ++jj) { float t = zr[i+jj]*zr[i+jj]; r[jj] = r[jj] + t; }
            }
            zz_lds[tid] = ((r[0]+r[1])+(r[2]+r[3])) + ((r[4]+r[5])+(r[6]+r[7]));
        }
    }
    // (zz_lds becomes visible to all at the first in-loop barrier.)

    float rb[4];  int rbj[4];
#pragma unroll
    for (int rr = 0; rr < 4; ++rr) { rb[rr] = __builtin_inff(); rbj[rr] = 0; }

    // --- Main loop: 16 tiles of 64 codes; 2 barriers/tile. ---
    for (int t = 0; t < NTILES; ++t) {
        // Write prefetched tile t into LDS (t=0: e_lds untouched; t>0: after tail barrier).
        *(float4*)&e_lds[((tid      ) >> 4) * ZSTR + ((tid      ) & 15) * 4] = pe0;
        *(float4*)&e_lds[((tid + 256) >> 4) * ZSTR + ((tid + 256) & 15) * 4] = pe1;
        *(float4*)&e_lds[((tid + 512) >> 4) * ZSTR + ((tid + 512) & 15) * 4] = pe2;
        *(float4*)&e_lds[((tid + 768) >> 4) * ZSTR + ((tid + 768) & 15) * 4] = pe3;
        __syncthreads();   // e tile t (and, at t=0, zz_lds) ready

        // Issue prefetch of tile t+1; latency hides under compute of tile t.
        if (t < NTILES - 1) {
            const float4* eg4 = (const float4*)(emb + (size_t)(t + 1) * TCODES * D);
            pe0 = eg4[tid];       pe1 = eg4[tid + 256];
            pe2 = eg4[tid + 512]; pe3 = eg4[tid + 768];
        }

        // 4 rows x 4 codes per lane; p0..p3 live in acc.{x,y,z,w} (verified order).
        float4 acc[4][4];
#pragma unroll
        for (int rr = 0; rr < 4; ++rr)
#pragma unroll
            for (int cc = 0; cc < 4; ++cc)
                acc[rr][cc] = make_float4(0.f, 0.f, 0.f, 0.f);

#pragma unroll 2
        for (int c = 0; c < 16; ++c) {
            float4 zf[4], ef[4];
#pragma unroll
            for (int rr = 0; rr < 4; ++rr)
                zf[rr] = *(const float4*)&z_lds[(zrow0 + 8*rr) * ZSTR + c * 4];
#pragma unroll
            for (int cc = 0; cc < 4; ++cc)
                ef[cc] = *(const float4*)&e_lds[((ch << 5) + jg + (cc << 3)) * ZSTR + c * 4];
#pragma unroll
            for (int rr = 0; rr < 4; ++rr)
#pragma unroll
                for (int cc = 0; cc < 4; ++cc) {
                    acc[rr][cc].x = fmaf(zf[rr].x, ef[cc].x, acc[rr][cc].x);
                    acc[rr][cc].y = fmaf(zf[rr].y, ef[cc].y, acc[rr][cc].y);
                    acc[rr][cc].z = fmaf(zf[rr].z, ef[cc].z, acc[rr][cc].z);
                    acc[rr][cc].w = fmaf(zf[rr].w, ef[cc].w, acc[rr][cc].w);
                }
        }

        // Fold: codes cbase + 8cc ascend with cc; tiles ascend with t -> strict <.
        const int cbase = t * TCODES + (ch << 5) + jg;
        const float ee0 = ee_lds[cbase];
        const float ee1 = ee_lds[cbase + 8];
        const float ee2 = ee_lds[cbase + 16];
        const float ee3 = ee_lds[cbase + 24];
#pragma unroll
        for (int rr = 0; rr < 4; ++rr) {
            const float zzv = zz_lds[zrow0 + 8*rr];
            float dot0 = (acc[rr][0].x + acc[rr][0].y) + (acc[rr][0].z + acc[rr][0].w);
            float dot1 = (acc[rr][1].x + acc[rr][1].y) + (acc[rr][1].z + acc[rr][1].w);
            float dot2 = (acc[rr][2].x + acc[rr][2].y) + (acc[rr][2].z + acc[rr][2].w);
            float dot3 = (acc[rr][3].x + acc[rr][3].y) + (acc[rr][3].z + acc[rr][3].w);
            float d0 = fmaf(-2.0f, dot0, zzv + ee0);   // mirrors np (zz+ee) rounding
            float d1 = fmaf(-2.0f, dot1, zzv + ee1);
            float d2 = fmaf(-2.0f, dot2, zzv + ee2);
            float d3 = fmaf(-2.0f, dot3, zzv + ee3);
            float cv = d0; int cj = cbase;
            if (d1 < cv) { cv = d1; cj = cbase + 8;  }
            if (d2 < cv) { cv = d2; cj = cbase + 16; }
            if (d3 < cv) { cv = d3; cj = cbase + 24; }
            if (cv < rb[rr]) { rb[rr] = cv; rbj[rr] = cj; }
        }
        __syncthreads();   // all reads of e_lds done before next overwrite
    }

    // --- 3-step butterfly over jg (lane bits 3..5): tie -> smaller index. ---
#pragma unroll
    for (int rr = 0; rr < 4; ++rr) {
        float bv = rb[rr]; int bj = rbj[rr];
#pragma unroll
        for (int off = 8; off <= 32; off <<= 1) {
            float ov = __shfl_xor(bv, off);
            int   oi = __shfl_xor(bj, off);
            if (ov < bv || (ov == bv && oi < bj)) { bv = ov; bj = oi; }
        }
        if (jg == 0) {
            smv[ch * ROWS + zrow0 + 8*rr] = bv;
            smi[ch * ROWS + zrow0 + 8*rr] = bj;
        }
    }
    __syncthreads();

    // --- Epilogue (R1's verified structure): thread handles row erow; wave eg
    //     stores f4-chunks c with (c>>2)==eg; wave 0 does loss + idx. ---
    const int erow = tid & 63;
    const int eg   = tid >> 6;

    float best = smv[erow]; int bi = smi[erow];
    {
        float v  = smv[ROWS + erow];
        int   ii = smi[ROWS + erow];
        if (v < best || (v == best && ii < bi)) { best = v; bi = ii; }
    }

    const float4* qe4 = (const float4*)(emb + ((size_t)bi << 6));
    float s = 0.f;
    float* orow = out_zq + (blockRow + erow) * D;
#pragma unroll
    for (int c = 0; c < 16; ++c) {
        float4 q  = qe4[c];
        float4 zv = *(const float4*)&z_lds[erow * ZSTR + c * 4];
        float d0 = q.x - zv.x, d1 = q.y - zv.y, d2 = q.z - zv.z, d3 = q.w - zv.w;
        s += d0*d0; s += d1*d1; s += d2*d2; s += d3*d3;
        if ((c >> 2) == eg) {                  // each (row,chunk) stored once
            // out_zq is d_out+1 (4B-aligned) -> dword stores.
            orow[4*c+0] = zv.x + d0; orow[4*c+1] = zv.y + d1;
            orow[4*c+2] = zv.z + d2; orow[4*c+3] = zv.w + d3;
        }
    }

    if (eg == 0) {                             // wave 0: loss + idx
        out_idx[blockRow + erow] = (float)bi;
#pragma unroll
        for (int off = 32; off; off >>= 1) s += __shfl_down(s, off);
        if (tid == 0) atomicAdd(out_loss, s * loss_scale);
    }
}

extern "C" void kernel_launch(void* const* d_in, const int* in_sizes, int n_in,
                              void* d_out, int out_size, void* d_ws, size_t ws_size,
                              hipStream_t stream) {
    const float* z   = (const float*)d_in[0];
    const float* emb = (const float*)d_in[1];
    const int nz = in_sizes[0];          // 4194304
    const int N  = nz / D;               // 65536 rows

    float* out      = (float*)d_out;
    float* out_zq   = out + 1;
    float* out_idx  = out + 1 + (size_t)nz;
    float* ee_ws    = (float*)d_ws;      // 4 KB

    const float loss_scale = 1.25f / (float)nz;

    hipMemsetAsync(out, 0, sizeof(float), stream);  // loss accumulator
    ee_kernel<<<NE / 64, 64, 0, stream>>>(emb, ee_ws);
    vq_kernel<<<N / ROWS, TPB, 0, stream>>>(z, emb, ee_ws, out, out_zq, out_idx,
                                            loss_scale);
}